// Round 3
// baseline (138.296 us; speedup 1.0000x reference)
//
#include <hip/hip_runtime.h>
#include <math.h>

#define B 8
#define NPTS 4096
#define QPT 8           // queries per thread in chamfer
#define THREADS 256

// ws layout: [partial: 2*B*S*NPTS floats][sums32: 32 floats]
// partial[((dir*B+b)*S + split)*NPTS + q]
// sums32[(dir*B+b)*2 + {0:sum_min, 1:sum_soft}]

// -------- K1: split-partial chamfer mins --------------------------------
// grid: dir(2) * b(8) * qchunk(2) * split(S) blocks
// dist(q,t) = |q|^2 + 2*s,  s = |t|^2/2 - q.t
template<int S, int LOG2S>
__global__ __launch_bounds__(THREADS) void chamfer_kernel(
    const float* __restrict__ pred, const float* __restrict__ targ,
    float* __restrict__ partial, float* __restrict__ sums32) {
  constexpr int REFS = NPTS / S;
  int id = blockIdx.x;
  int split  = id & (S - 1);
  int qchunk = (id >> LOG2S) & 1;
  int b      = (id >> (LOG2S + 1)) & 7;
  int dir    = id >> (LOG2S + 4);
  const float* qp = dir ? targ : pred;
  const float* rp = dir ? pred : targ;

  int tid = threadIdx.x;
  if (id == 0 && tid < 32) sums32[tid] = 0.f;   // zero accumulators for K2

  __shared__ float4 refs[REFS];   // x, y, z, 0.5*|t|^2
  const float* rb = rp + ((size_t)b * NPTS + (size_t)split * REFS) * 3;
  for (int i = tid; i < REFS; i += THREADS) {
    float x = rb[i * 3 + 0], y = rb[i * 3 + 1], z = rb[i * 3 + 2];
    refs[i] = make_float4(x, y, z, 0.5f * (x * x + y * y + z * z));
  }
  __syncthreads();

  const float* qb = qp + (size_t)b * NPTS * 3;
  int q0 = qchunk * (QPT * THREADS) + tid;
  float qx[QPT], qy[QPT], qz[QPT], vmin[QPT];
#pragma unroll
  for (int i = 0; i < QPT; ++i) {
    int q = q0 + i * THREADS;
    qx[i] = qb[q * 3 + 0];
    qy[i] = qb[q * 3 + 1];
    qz[i] = qb[q * 3 + 2];
    vmin[i] = 3.4e38f;
  }

  for (int j = 0; j < REFS; j += 4) {
    float4 t0 = refs[j + 0];
    float4 t1 = refs[j + 1];
    float4 t2 = refs[j + 2];
    float4 t3 = refs[j + 3];
#pragma unroll
    for (int i = 0; i < QPT; ++i) {
      float s0 = fmaf(-qx[i], t0.x, fmaf(-qy[i], t0.y, fmaf(-qz[i], t0.z, t0.w)));
      float s1 = fmaf(-qx[i], t1.x, fmaf(-qy[i], t1.y, fmaf(-qz[i], t1.z, t1.w)));
      float s2 = fmaf(-qx[i], t2.x, fmaf(-qy[i], t2.y, fmaf(-qz[i], t2.z, t2.w)));
      float s3 = fmaf(-qx[i], t3.x, fmaf(-qy[i], t3.y, fmaf(-qz[i], t3.z, t3.w)));
      vmin[i] = fminf(vmin[i], fminf(fminf(s0, s1), fminf(s2, s3)));
    }
  }

  size_t base = (((size_t)dir * B + b) * S + split) * NPTS;
#pragma unroll
  for (int i = 0; i < QPT; ++i) {
    float qn = fmaf(qx[i], qx[i], fmaf(qy[i], qy[i], qz[i] * qz[i]));
    partial[base + q0 + i * THREADS] = fmaf(2.f, vmin[i], qn);
  }
}

// -------- K2: min over splits, sums, atomic accumulate ------------------
// grid: dir(2) * b(8) * chunk(8) = 128 blocks
template<int S>
__global__ __launch_bounds__(THREADS) void reduce_kernel(
    const float* __restrict__ partial, float* __restrict__ sums32) {
  int id = blockIdx.x;
  int chunk = id & 7;
  int b   = (id >> 3) & 7;
  int dir = id >> 6;
  int tid = threadIdx.x;
  size_t pb = ((size_t)dir * B + b) * S * NPTS;

  float s_min = 0.f, s_soft = 0.f;
#pragma unroll
  for (int i = 0; i < 2; ++i) {
    int q = chunk * 512 + i * 256 + tid;
    float m = 3.4e38f;
#pragma unroll
    for (int s = 0; s < S; ++s)
      m = fminf(m, partial[pb + (size_t)s * NPTS + q]);
    s_min  += m;
    s_soft += __expf(-5000.0f * m);   // 1/(2*sigma^2) = 5000
  }
  for (int off = 32; off > 0; off >>= 1) {
    s_min  += __shfl_down(s_min,  off);
    s_soft += __shfl_down(s_soft, off);
  }
  __shared__ float red[8];
  int wave = tid >> 6, lane = tid & 63;
  if (lane == 0) { red[wave * 2] = s_min; red[wave * 2 + 1] = s_soft; }
  __syncthreads();
  if (tid == 0) {
    float a = 0.f, c = 0.f;
    for (int w = 0; w < 4; ++w) { a += red[w * 2]; c += red[w * 2 + 1]; }
    atomicAdd(&sums32[(dir * B + b) * 2 + 0], a);
    atomicAdd(&sums32[(dir * B + b) * 2 + 1], c);
  }
}

// -------- K3: full MLP + softmax/NLL + final combine (1 block) ----------
__global__ __launch_bounds__(1024) void final_kernel(
    const float* __restrict__ x,
    const float* __restrict__ W1, const float* __restrict__ b1,
    const float* __restrict__ W2, const float* __restrict__ b2,
    const float* __restrict__ W3, const float* __restrict__ b3,
    const int* __restrict__ labels, const float* __restrict__ sums32,
    const float* __restrict__ w, float* __restrict__ out) {
  int tid = threadIdx.x;
  __shared__ float xs[8 * 512];       // 16 KB
  __shared__ float pp[4 * 8 * 256];   // 32 KB partials (reused for layer 2)
  __shared__ float h1[8 * 256];       // 8 KB
  __shared__ float h2[8 * 128];       // 4 KB
  __shared__ float lg[48];
  __shared__ float nlls[8];

  for (int i = tid; i < 4096; i += 1024) xs[i] = x[i];
  __syncthreads();

  // L1 partials: thread -> (j = tid&255, kc = tid>>8), k in [kc*128, kc*128+128)
  {
    int j = tid & 255, kc = tid >> 8;
    float acc[8];
#pragma unroll
    for (int bb = 0; bb < 8; ++bb) acc[bb] = 0.f;
    const float* wp = W1 + (size_t)(kc * 128) * 256 + j;
    for (int k = 0; k < 128; ++k) {
      float wv = wp[k * 256];
      int kk = kc * 128 + k;
#pragma unroll
      for (int bb = 0; bb < 8; ++bb)
        acc[bb] = fmaf(xs[bb * 512 + kk], wv, acc[bb]);
    }
#pragma unroll
    for (int bb = 0; bb < 8; ++bb) pp[(kc * 8 + bb) * 256 + j] = acc[bb];
  }
  __syncthreads();
  // combine L1 + relu
  for (int i = tid; i < 2048; i += 1024) {
    int b = i >> 8, j = i & 255;
    float a = b1[j];
#pragma unroll
    for (int kc = 0; kc < 4; ++kc) a += pp[(kc * 8 + b) * 256 + j];
    h1[b * 256 + j] = fmaxf(a, 0.f);
  }
  __syncthreads();

  // L2 partials: thread -> (j = tid&127, kc = tid>>7), k in [kc*32, kc*32+32)
  {
    int j = tid & 127, kc = tid >> 7;
    float acc[8];
#pragma unroll
    for (int bb = 0; bb < 8; ++bb) acc[bb] = 0.f;
    const float* wp = W2 + (size_t)(kc * 32) * 128 + j;
    for (int k = 0; k < 32; ++k) {
      float wv = wp[k * 128];
      int kk = kc * 32 + k;
#pragma unroll
      for (int bb = 0; bb < 8; ++bb)
        acc[bb] = fmaf(h1[bb * 256 + kk], wv, acc[bb]);
    }
#pragma unroll
    for (int bb = 0; bb < 8; ++bb) pp[(kc * 8 + bb) * 128 + j] = acc[bb];
  }
  __syncthreads();
  // combine L2 + relu
  {
    int b = tid >> 7, j = tid & 127;
    float a = b2[j];
#pragma unroll
    for (int kc = 0; kc < 8; ++kc) a += pp[(kc * 8 + b) * 128 + j];
    h2[b * 128 + j] = fmaxf(a, 0.f);
  }
  __syncthreads();

  // L3 logits
  if (tid < 48) {
    int b = tid / 6, d = tid % 6;
    float acc = b3[d];
#pragma unroll 8
    for (int k = 0; k < 128; ++k) acc = fmaf(h2[b * 128 + k], W3[k * 6 + d], acc);
    lg[tid] = acc;
  }
  __syncthreads();
  if (tid < 8) {
    int b = tid;
    float mx = lg[b * 6];
    for (int d = 1; d < 6; ++d) mx = fmaxf(mx, lg[b * 6 + d]);
    float se = 0.f;
    for (int d = 0; d < 6; ++d) se += __expf(lg[b * 6 + d] - mx);
    int lab = labels[b];
    nlls[b] = -(lg[b * 6 + lab] - mx - __logf(se));
  }
  __syncthreads();
  if (tid == 0) {
    float chamfer = 0.f, prec = 0.f, rec = 0.f, dsw = 0.f, dom = 0.f;
    for (int b = 0; b < B; ++b) {
      float sa  = sums32[(0 * B + b) * 2 + 0];
      float ssa = sums32[(0 * B + b) * 2 + 1];
      float sb  = sums32[(1 * B + b) * 2 + 0];
      float ssb = sums32[(1 * B + b) * 2 + 1];
      float ma = sa / 4096.f, mb = sb / 4096.f;
      float p = ssa / 4096.f, r = ssb / 4096.f;
      chamfer += ma + mb;
      prec += p; rec += r;
      float f_i = 2.f * p * r / (p + r + 1e-8f);
      float loss_i = ma + mb + 0.1f * (1.f - f_i);
      dsw += w[b] * loss_i;
      dom += nlls[b];
    }
    chamfer *= (1.f / B); prec *= (1.f / B); rec *= (1.f / B);
    dsw *= (1.f / B); dom *= (1.f / B);
    float fscore = 2.f * prec * rec / (prec + rec + 1e-8f);
    float task = chamfer + 0.1f * (1.f - fscore);
    out[0] = 1.0f * task + 0.1f * dom + dsw;
  }
}

extern "C" void kernel_launch(void* const* d_in, const int* in_sizes, int n_in,
                              void* d_out, int out_size, void* d_ws, size_t ws_size,
                              hipStream_t stream) {
  const float* pred   = (const float*)d_in[0];
  const float* targ   = (const float*)d_in[1];
  const float* x      = (const float*)d_in[2];
  const float* wgt    = (const float*)d_in[3];
  const float* W1     = (const float*)d_in[4];
  const float* b1     = (const float*)d_in[5];
  const float* W2     = (const float*)d_in[6];
  const float* b2     = (const float*)d_in[7];
  const float* W3     = (const float*)d_in[8];
  const float* b3     = (const float*)d_in[9];
  const int*   labels = (const int*)d_in[10];
  float* out = (float*)d_out;

  char* ws = (char*)d_ws;
  float* partial = (float*)ws;

  size_t need16 = ((size_t)2 * B * 16 * NPTS + 32) * sizeof(float);
  if (ws_size >= need16) {
    float* sums32 = partial + (size_t)2 * B * 16 * NPTS;
    hipLaunchKernelGGL((chamfer_kernel<16, 4>), dim3(1024), dim3(THREADS), 0,
                       stream, pred, targ, partial, sums32);
    hipLaunchKernelGGL((reduce_kernel<16>), dim3(128), dim3(THREADS), 0,
                       stream, partial, sums32);
    hipLaunchKernelGGL(final_kernel, dim3(1), dim3(1024), 0, stream,
                       x, W1, b1, W2, b2, W3, b3, labels, sums32, wgt, out);
  } else {
    float* sums32 = partial + (size_t)2 * B * 8 * NPTS;
    hipLaunchKernelGGL((chamfer_kernel<8, 3>), dim3(512), dim3(THREADS), 0,
                       stream, pred, targ, partial, sums32);
    hipLaunchKernelGGL((reduce_kernel<8>), dim3(128), dim3(THREADS), 0,
                       stream, partial, sums32);
    hipLaunchKernelGGL(final_kernel, dim3(1), dim3(1024), 0, stream,
                       x, W1, b1, W2, b2, W3, b3, labels, sums32, wgt, out);
  }
}

// Round 4
// 112.594 us; speedup vs baseline: 1.2283x; 1.2283x over previous
//
#include <hip/hip_runtime.h>
#include <math.h>

#define B 8
#define NPTS 4096
#define QPT 8           // queries per thread in chamfer
#define THREADS 256

// ws layout: [partial: 2*B*S*NPTS f][sums32: 32 f][h1p: 64*256 f][h2p: 16*128 f]
// partial[((dir*B+b)*S + split)*NPTS + q]
// sums32[(dir*B+b)*2 + {0:min,1:soft}]  (atomic-accumulated by D2)

// ======== D1: 64 MLP-L1 blocks + 32*S chamfer blocks ====================
// dist(q,t) = |q|^2 + 2*s,  s = |t|^2/2 - q.t
template<int S, int LOG2S>
__global__ __launch_bounds__(THREADS, 4) void d1_kernel(
    const float* __restrict__ pred, const float* __restrict__ targ,
    const float* __restrict__ x, const float* __restrict__ W1,
    float* __restrict__ partial, float* __restrict__ sums32,
    float* __restrict__ h1p) {
  constexpr int REFS = NPTS / S;
  int id = blockIdx.x;
  int tid = threadIdx.x;

  __shared__ float4 refs[REFS];
  __shared__ float xs[64];

  if (id < 64) {
    // ---- MLP layer-1 partials: h1p[(b*8+kc)*256+j] = sum_k x[b,k]W1[k,j]
    if (id == 0 && tid < 32) sums32[tid] = 0.f;   // init for D2 atomics
    int b = id >> 3, kc = id & 7;
    if (tid < 64) xs[tid] = x[b * 512 + kc * 64 + tid];
    __syncthreads();
    float acc = 0.f;
    const float* w = W1 + (size_t)(kc * 64) * 256 + tid;
#pragma unroll 8
    for (int k = 0; k < 64; ++k) acc = fmaf(xs[k], w[k * 256], acc);
    h1p[(b * 8 + kc) * 256 + tid] = acc;
    return;
  }

  // ---- chamfer split-partial mins
  int cid = id - 64;
  int split  = cid & (S - 1);
  int qchunk = (cid >> LOG2S) & 1;
  int b      = (cid >> (LOG2S + 1)) & 7;
  int dir    = cid >> (LOG2S + 4);          // grid = 64 + 32*S -> dir in {0,1}
  const float* qp = dir ? targ : pred;
  const float* rp = dir ? pred : targ;

  const float* rb = rp + ((size_t)b * NPTS + (size_t)split * REFS) * 3;
  for (int i = tid; i < REFS; i += THREADS) {
    float xx = rb[i * 3 + 0], yy = rb[i * 3 + 1], zz = rb[i * 3 + 2];
    refs[i] = make_float4(xx, yy, zz, 0.5f * (xx * xx + yy * yy + zz * zz));
  }
  __syncthreads();

  const float* qb = qp + (size_t)b * NPTS * 3;
  int q0 = qchunk * (QPT * THREADS) + tid;
  float qx[QPT], qy[QPT], qz[QPT], vmin[QPT];
#pragma unroll
  for (int i = 0; i < QPT; ++i) {
    int q = q0 + i * THREADS;
    qx[i] = qb[q * 3 + 0];
    qy[i] = qb[q * 3 + 1];
    qz[i] = qb[q * 3 + 2];
    vmin[i] = 3.4e38f;
  }

  for (int j = 0; j < REFS; j += 8) {
    float4 t[8];
#pragma unroll
    for (int u = 0; u < 8; ++u) t[u] = refs[j + u];
#pragma unroll
    for (int i = 0; i < QPT; ++i) {
      float s[8];
#pragma unroll
      for (int u = 0; u < 8; ++u)
        s[u] = fmaf(-qx[i], t[u].x,
               fmaf(-qy[i], t[u].y, fmaf(-qz[i], t[u].z, t[u].w)));
      float m01 = fminf(s[0], s[1]), m23 = fminf(s[2], s[3]);
      float m45 = fminf(s[4], s[5]), m67 = fminf(s[6], s[7]);
      vmin[i] = fminf(vmin[i],
                      fminf(fminf(m01, m23), fminf(m45, m67)));
    }
  }

  size_t base = (((size_t)dir * B + b) * S + split) * NPTS;
#pragma unroll
  for (int i = 0; i < QPT; ++i) {
    float qn = fmaf(qx[i], qx[i], fmaf(qy[i], qy[i], qz[i] * qz[i]));
    partial[base + q0 + i * THREADS] = fmaf(2.f, vmin[i], qn);
  }
}

// ======== D2: 256 reduce blocks + 16 MLP-L2 blocks ======================
template<int S>
__global__ __launch_bounds__(THREADS) void d2_kernel(
    const float* __restrict__ partial, float* __restrict__ sums32,
    const float* __restrict__ h1p, const float* __restrict__ b1,
    const float* __restrict__ W2, float* __restrict__ h2p) {
  int id = blockIdx.x;
  int tid = threadIdx.x;

  if (id >= 256) {
    // ---- L2 partials: h2p[(b*2+half)*128+j] over k in [half*128, +128)
    int lid = id - 256;
    int b = lid >> 1, half = lid & 1;
    __shared__ float hs[128];
    if (tid < 128) {
      int k = half * 128 + tid;
      float a = b1[k];
#pragma unroll
      for (int p = 0; p < 8; ++p) a += h1p[(b * 8 + p) * 256 + k];
      hs[tid] = fmaxf(a, 0.f);
    }
    __syncthreads();
    if (tid < 128) {
      float acc = 0.f;
      const float* w = W2 + (size_t)(half * 128) * 128 + tid;
#pragma unroll 8
      for (int k = 0; k < 128; ++k) acc = fmaf(hs[k], w[k * 128], acc);
      h2p[(b * 2 + half) * 128 + tid] = acc;
    }
    return;
  }

  // ---- reduce: min over S splits, sum min and exp
  int chunk = id & 15;
  int b   = (id >> 4) & 7;
  int dir = id >> 7;
  size_t pb = ((size_t)dir * B + b) * S * NPTS;
  int q = chunk * 256 + tid;

  float m = 3.4e38f;
#pragma unroll
  for (int s = 0; s < S; ++s)
    m = fminf(m, partial[pb + (size_t)s * NPTS + q]);
  float s_min = m;
  float s_soft = __expf(-5000.0f * m);   // 1/(2*sigma^2) = 5000

  for (int off = 32; off > 0; off >>= 1) {
    s_min  += __shfl_down(s_min,  off);
    s_soft += __shfl_down(s_soft, off);
  }
  __shared__ float red[8];
  int wave = tid >> 6, lane = tid & 63;
  if (lane == 0) { red[wave * 2] = s_min; red[wave * 2 + 1] = s_soft; }
  __syncthreads();
  if (tid == 0) {
    float a = 0.f, c = 0.f;
    for (int w = 0; w < 4; ++w) { a += red[w * 2]; c += red[w * 2 + 1]; }
    atomicAdd(&sums32[(dir * B + b) * 2 + 0], a);
    atomicAdd(&sums32[(dir * B + b) * 2 + 1], c);
  }
}

// ======== D3: L2 combine + L3 + softmax/NLL + final combine (1 block) ===
__global__ __launch_bounds__(THREADS) void final_kernel(
    const float* __restrict__ h2p, const float* __restrict__ b2,
    const float* __restrict__ W3, const float* __restrict__ b3,
    const int* __restrict__ labels, const float* __restrict__ sums32,
    const float* __restrict__ w, float* __restrict__ out) {
  int tid = threadIdx.x;
  __shared__ float h2s[8 * 128];
  __shared__ float lg[48];
  __shared__ float nlls[8];

  for (int i = tid; i < 1024; i += THREADS) {
    int b = i >> 7, j = i & 127;
    float a = b2[j] + h2p[(b * 2 + 0) * 128 + j] + h2p[(b * 2 + 1) * 128 + j];
    h2s[i] = fmaxf(a, 0.f);
  }
  __syncthreads();
  if (tid < 48) {
    int b = tid / 6, d = tid % 6;
    float acc = b3[d];
#pragma unroll 8
    for (int k = 0; k < 128; ++k) acc = fmaf(h2s[b * 128 + k], W3[k * 6 + d], acc);
    lg[tid] = acc;
  }
  __syncthreads();
  if (tid < 8) {
    int b = tid;
    float mx = lg[b * 6];
    for (int d = 1; d < 6; ++d) mx = fmaxf(mx, lg[b * 6 + d]);
    float se = 0.f;
    for (int d = 0; d < 6; ++d) se += __expf(lg[b * 6 + d] - mx);
    int lab = labels[b];
    nlls[b] = -(lg[b * 6 + lab] - mx - __logf(se));
  }
  __syncthreads();
  if (tid == 0) {
    float chamfer = 0.f, prec = 0.f, rec = 0.f, dsw = 0.f, dom = 0.f;
    for (int b = 0; b < B; ++b) {
      float sa  = sums32[(0 * B + b) * 2 + 0];
      float ssa = sums32[(0 * B + b) * 2 + 1];
      float sb  = sums32[(1 * B + b) * 2 + 0];
      float ssb = sums32[(1 * B + b) * 2 + 1];
      float ma = sa / 4096.f, mb = sb / 4096.f;
      float p = ssa / 4096.f, r = ssb / 4096.f;
      chamfer += ma + mb;
      prec += p; rec += r;
      float f_i = 2.f * p * r / (p + r + 1e-8f);
      float loss_i = ma + mb + 0.1f * (1.f - f_i);
      dsw += w[b] * loss_i;
      dom += nlls[b];
    }
    chamfer *= (1.f / B); prec *= (1.f / B); rec *= (1.f / B);
    dsw *= (1.f / B); dom *= (1.f / B);
    float fscore = 2.f * prec * rec / (prec + rec + 1e-8f);
    float task = chamfer + 0.1f * (1.f - fscore);
    out[0] = 1.0f * task + 0.1f * dom + dsw;
  }
}

template<int S, int LOG2S>
static void run_pipeline(const float* pred, const float* targ, const float* x,
                         const float* wgt, const float* W1, const float* b1,
                         const float* W2, const float* b2, const float* W3,
                         const float* b3, const int* labels, float* out,
                         char* ws, hipStream_t stream) {
  float* partial = (float*)ws;
  float* sums32  = partial + (size_t)2 * B * S * NPTS;
  float* h1p     = sums32 + 32;
  float* h2p     = h1p + 64 * 256;

  hipLaunchKernelGGL((d1_kernel<S, LOG2S>), dim3(64 + 32 * S), dim3(THREADS),
                     0, stream, pred, targ, x, W1, partial, sums32, h1p);
  hipLaunchKernelGGL((d2_kernel<S>), dim3(256 + 16), dim3(THREADS), 0, stream,
                     partial, sums32, h1p, b1, W2, h2p);
  hipLaunchKernelGGL(final_kernel, dim3(1), dim3(THREADS), 0, stream,
                     h2p, b2, W3, b3, labels, sums32, wgt, out);
}

extern "C" void kernel_launch(void* const* d_in, const int* in_sizes, int n_in,
                              void* d_out, int out_size, void* d_ws, size_t ws_size,
                              hipStream_t stream) {
  const float* pred   = (const float*)d_in[0];
  const float* targ   = (const float*)d_in[1];
  const float* x      = (const float*)d_in[2];
  const float* wgt    = (const float*)d_in[3];
  const float* W1     = (const float*)d_in[4];
  const float* b1     = (const float*)d_in[5];
  const float* W2     = (const float*)d_in[6];
  const float* b2     = (const float*)d_in[7];
  const float* W3     = (const float*)d_in[8];
  const float* b3     = (const float*)d_in[9];
  const int*   labels = (const int*)d_in[10];
  float* out = (float*)d_out;
  char* ws = (char*)d_ws;

  auto need = [](int S) {
    return ((size_t)2 * B * S * NPTS + 32 + 64 * 256 + 16 * 128) * sizeof(float);
  };
  if (ws_size >= need(32))
    run_pipeline<32, 5>(pred, targ, x, wgt, W1, b1, W2, b2, W3, b3, labels,
                        out, ws, stream);
  else if (ws_size >= need(16))
    run_pipeline<16, 4>(pred, targ, x, wgt, W1, b1, W2, b2, W3, b3, labels,
                        out, ws, stream);
  else
    run_pipeline<8, 3>(pred, targ, x, wgt, W1, b1, W2, b2, W3, b3, labels,
                       out, ws, stream);
}